// Round 8
// baseline (524.903 us; speedup 1.0000x reference)
//
#include <hip/hip_runtime.h>
#include <hip/hip_bf16.h>

typedef unsigned short bfu;
typedef __attribute__((ext_vector_type(8))) short short8;
typedef __attribute__((ext_vector_type(4))) float f32x4;

__device__ __forceinline__ bfu f2bf(float f) {
  return __builtin_bit_cast(bfu, __float2bfloat16(f));
}

__device__ __forceinline__ void gld16(const void* g, void* l) {
  __builtin_amdgcn_global_load_lds(
      (const __attribute__((address_space(1))) void*)g,
      (__attribute__((address_space(3))) void*)l, 16, 0, 0);
}

// ---- swizzle for [rows][64]-bf16 tiles (128B rows, 8 x 16B slots per row)
__device__ __forceinline__ int swz8(int row, int sl) {
  return (row << 7) + (((sl ^ (row & 7)) & 7) << 4);
}

// ---- swizzle for [rows][32]-bf16 tiles (64B rows) used by row_gemm --------
__device__ __forceinline__ int swz(int row, int slot) {
  const int unit = row >> 1;
  const int s8 = ((row & 1) << 2) | slot;
  return (unit << 7) + (((s8 ^ unit) & 7) << 4) + ((s8 >> 3) << 7);
}
__device__ __forceinline__ void unswz(int p, int& row, int& colel) {
  const int unit = p >> 7;
  const int s8 = ((p >> 4) & 7) ^ (unit & 7);
  row = (unit << 1) | (s8 >> 2);
  colel = (s8 & 3) << 3;
}

// ---------------- weight prep in ONE launch ---------------------------------
// wqkvT/woT: row-major transposed [n][k] (bf16) for the staged GEMMs.
// w1f/w2f: FRAGMENT-MAJOR for ffn_fused: frag[(ntile*KS + ks)*512 + lane*8 + j]
// holds W[k][n] with n = ntile*16 + (lane&15), k = ks*32 + ((lane>>4)<<3) + j.
__global__ void transpose_all(const float* __restrict__ Wq, const float* __restrict__ Wk,
                              const float* __restrict__ Wv, const float* __restrict__ Wo,
                              const float* __restrict__ W1, const float* __restrict__ W2,
                              bfu* __restrict__ wqkvT, bfu* __restrict__ woT,
                              bfu* __restrict__ w1f, bfu* __restrict__ w2f) {
  int idx = blockIdx.x * 256 + threadIdx.x;
  if (idx < 4 * 147456) {
    int r = idx / 147456, i = idx - r * 147456;
    int k = i / 384, n = i - k * 384;
    const float* W = r == 0 ? Wq : r == 1 ? Wk : r == 2 ? Wv : Wo;
    bfu* dst = r < 3 ? wqkvT + r * 147456 : woT;
    dst[n * 384 + k] = f2bf(W[i]);
  } else if (idx < 4 * 147456 + 589824) {
    int i = idx - 4 * 147456;                    // W1: [384][1536]
    int k = i / 1536, n = i - k * 1536;
    int di = (((n >> 4) * 12 + (k >> 5)) << 9) +
             (((((k >> 3) & 3) << 4) | (n & 15)) << 3) + (k & 7);
    w1f[di] = f2bf(W1[i]);
  } else if (idx < 4 * 147456 + 2 * 589824) {
    int i = idx - 4 * 147456 - 589824;           // W2: [1536][384]
    int k = i / 384, n = i - k * 384;
    int di = (((n >> 4) * 48 + (k >> 5)) << 9) +
             (((((k >> 3) & 3) << 4) | (n & 15)) << 3) + (k & 7);
    w2f[di] = f2bf(W2[i]);
  }
}

// ---------------- LayerNorm: one wave per row of 384 ------------------------
__launch_bounds__(256)
__global__ void ln_kernel(const float* __restrict__ in, const float* __restrict__ g,
                          const float* __restrict__ be, bfu* __restrict__ out) {
  const int wv = threadIdx.x >> 6, ln = threadIdx.x & 63;
  const size_t row = (size_t)blockIdx.x * 4 + wv;
  const float* p = in + row * 384;
  float v[6], s = 0.f, ss = 0.f;
#pragma unroll
  for (int i = 0; i < 6; i++) { v[i] = p[i * 64 + ln]; s += v[i]; ss += v[i] * v[i]; }
#pragma unroll
  for (int m = 1; m < 64; m <<= 1) { s += __shfl_xor(s, m); ss += __shfl_xor(ss, m); }
  const float mean = s * (1.f / 384.f);
  const float rs = rsqrtf(ss * (1.f / 384.f) - mean * mean + 1e-5f);
  bfu* q = out + row * 384;
#pragma unroll
  for (int i = 0; i < 6; i++) {
    const int c = i * 64 + ln;
    q[c] = f2bf((v[i] - mean) * rs * g[c] + be[c]);
  }
}

// ---------------- fused FFN: out = relu(h2@W1+b1)@W2 + b2 + x ---------------
// 64-row m-panel per block (grid 1024), 8 waves. h2-panel (64x384 bf16) in LDS
// once. 12 chunks of 128 FFN-cols: stage1 (h2@W1chunk, K=384) with A from LDS
// + B streamed coalesced from frag-major w1f (registers only, no barriers);
// relu+bf16 -> T in LDS (C-layout -> A-frag round-trip, attention idiom);
// stage2 acc2 += T @ W2chunk (frag-major w2f). Epilogue +b2 +x -> fp32.
__launch_bounds__(512)
__global__ void ffn_fused(const bfu* __restrict__ h2, const bfu* __restrict__ w1f,
                          const bfu* __restrict__ w2f, const float* __restrict__ b1,
                          const float* __restrict__ b2, const float* __restrict__ x,
                          float* __restrict__ out) {
  __shared__ bfu h2s[64][392];   // +8 pad: row stride 196 dw -> bank-rotate 4
  __shared__ bfu Ts[64][136];    // +8 pad
  const int tid = threadIdx.x, wv = tid >> 6, ln = tid & 63;
  const int m0 = blockIdx.x << 6;
  const int fr = ln & 15, fs = ln >> 4;
  const int rq = fs << 2;
  const int wr1 = wv >> 2, wc1 = wv & 3;   // stage1: 2m x 4n, wave 32x32
  const int wr2 = wv >> 2, wc2 = wv & 3;   // stage2: 2m x 4n, wave 32x96

  {  // stage h2 panel, fully coalesced (8 threads per row, 6 short8 each)
    const int row = tid >> 3, seg = tid & 7;
    const bfu* src = h2 + (size_t)(m0 + row) * 384 + seg * 48;
    bfu* dst = &h2s[row][seg * 48];
#pragma unroll
    for (int i = 0; i < 6; i++)
      *(short8*)(dst + i * 8) = *(const short8*)(src + i * 8);
  }
  __syncthreads();

  f32x4 acc2[2][6];
#pragma unroll
  for (int i = 0; i < 2; i++)
#pragma unroll
    for (int j = 0; j < 6; j++) acc2[i][j] = f32x4{0.f, 0.f, 0.f, 0.f};

  for (int c = 0; c < 12; ++c) {
    // ---- stage1: C1[64][128] = h2s @ W1[:, c*128 .. +128)
    f32x4 acc1[2][2];
#pragma unroll
    for (int i = 0; i < 2; i++)
#pragma unroll
      for (int j = 0; j < 2; j++) acc1[i][j] = f32x4{0.f, 0.f, 0.f, 0.f};
#pragma unroll
    for (int ks = 0; ks < 12; ++ks) {
      short8 a1[2], bf1[2];
#pragma unroll
      for (int mi = 0; mi < 2; mi++)
        a1[mi] = *(const short8*)&h2s[wr1 * 32 + mi * 16 + fr][ks * 32 + rq * 2];
#pragma unroll
      for (int ni = 0; ni < 2; ni++)
        bf1[ni] = *(const short8*)(w1f +
            ((size_t)((c * 8 + wc1 * 2 + ni) * 12 + ks) << 9) + (ln << 3));
#pragma unroll
      for (int mi = 0; mi < 2; mi++)
#pragma unroll
        for (int ni = 0; ni < 2; ni++)
          acc1[mi][ni] = __builtin_amdgcn_mfma_f32_16x16x32_bf16(
              a1[mi], bf1[ni], acc1[mi][ni], 0, 0, 0);
    }
    // ---- T handoff: bias + relu + bf16, C-layout write (prev stage2 done)
    __syncthreads();
#pragma unroll
    for (int mi = 0; mi < 2; mi++) {
#pragma unroll
      for (int ni = 0; ni < 2; ni++) {
        const int colc = wc1 * 32 + ni * 16 + fr;
        const float bv = b1[c * 128 + colc];
#pragma unroll
        for (int r = 0; r < 4; r++) {
          float v = fmaxf(acc1[mi][ni][r] + bv, 0.f);
          Ts[wr1 * 32 + mi * 16 + rq + r][colc] = f2bf(v);
        }
      }
    }
    __syncthreads();
    // ---- stage2: acc2 += Ts @ W2[c*128 .. +128, :]
#pragma unroll
    for (int ks = 0; ks < 4; ++ks) {
      short8 a2[2], bf2[6];
#pragma unroll
      for (int mi = 0; mi < 2; mi++)
        a2[mi] = *(const short8*)&Ts[wr2 * 32 + mi * 16 + fr][ks * 32 + rq * 2];
#pragma unroll
      for (int ni = 0; ni < 6; ni++)
        bf2[ni] = *(const short8*)(w2f +
            ((size_t)((wc2 * 6 + ni) * 48 + c * 4 + ks) << 9) + (ln << 3));
#pragma unroll
      for (int mi = 0; mi < 2; mi++)
#pragma unroll
        for (int ni = 0; ni < 6; ni++)
          acc2[mi][ni] = __builtin_amdgcn_mfma_f32_16x16x32_bf16(
              a2[mi], bf2[ni], acc2[mi][ni], 0, 0, 0);
    }
  }

  // ---- epilogue: out = acc2 + b2 + x (fp32)
#pragma unroll
  for (int mi = 0; mi < 2; mi++) {
#pragma unroll
    for (int ni = 0; ni < 6; ni++) {
      const int col = wc2 * 96 + ni * 16 + fr;
      const float bv = b2[col];
#pragma unroll
      for (int r = 0; r < 4; r++) {
        const int row = m0 + wr2 * 32 + mi * 16 + rq + r;
        const size_t idx = (size_t)row * 384 + col;
        out[idx] = acc2[mi][ni][r] + bv + x[idx];
      }
    }
  }
}

// ---------------- fat-tile 4-phase GEMM (QKV): C = A @ Bt^T -----------------
template <int WM, int WN, int OUTBF>
__launch_bounds__(512)
__global__ void gemm_ph(const bfu* __restrict__ A, const bfu* __restrict__ Bt,
                        void* __restrict__ Cout, int N, int K, int ntn) {
  constexpr int BM = WM * 32;
  constexpr int BN = WN * 64;
  constexpr int ACH = BM / 64;
  constexpr int BCH = BN / 64;
  __shared__ bfu sm[2][(BM + BN) * 64];
  const int tid = threadIdx.x;
  const int wv = tid >> 6, ln = tid & 63;
  const int cpx = gridDim.x >> 3;
  const int wg = (blockIdx.x & 7) * cpx + (blockIdx.x >> 3);
  const int bm = wg / ntn, bn = wg - bm * ntn;
  const int m0 = bm * BM, n0 = bn * BN;
  const int wr = wv >> 2, wc = wv & 3;
  const int fr = ln & 15, fslot = ln >> 4;
  const int lr = ln >> 3, lsl = (ln & 7) ^ lr;

  f32x4 acc[WM][WN];
#pragma unroll
  for (int i = 0; i < WM; i++)
#pragma unroll
    for (int j = 0; j < WN; j++) acc[i][j] = f32x4{0.f, 0.f, 0.f, 0.f};

  auto stageA = [&](int s, int kt) {
    char* smA = (char*)sm[s];
    const int col = (kt << 6) + (lsl << 3);
#pragma unroll
    for (int i = 0; i < ACH; ++i) {
      const int c = wv * ACH + i;
      gld16(A + (size_t)(m0 + (c << 3) + lr) * K + col, smA + (c << 10));
    }
  };
  auto stageB = [&](int s, int kt) {
    char* smB = (char*)sm[s] + BM * 128;
    const int col = (kt << 6) + (lsl << 3);
#pragma unroll
    for (int i = 0; i < BCH; ++i) {
      const int c = wv * BCH + i;
      gld16(Bt + (size_t)(n0 + (c << 3) + lr) * K + col, smB + (c << 10));
    }
  };

  const int nk = K >> 6;
  stageA(0, 0);
  stageB(0, 0);
  asm volatile("s_waitcnt vmcnt(0)" ::: "memory");
  __builtin_amdgcn_s_barrier();

  for (int kt = 0; kt < nk; ++kt) {
    const int cur = kt & 1;
    const char* smA = (const char*)sm[cur];
    const char* smB = smA + BM * 128;
    short8 bf[2][WN];
#pragma unroll
    for (int ph = 0; ph < 4; ++ph) {
      const int mh = ph >> 1, ks = ph & 1;
      short8 af[WM / 2];
#pragma unroll
      for (int i = 0; i < WM / 2; ++i)
        af[i] = *(const short8*)(smA +
            swz8(wr * (WM * 16) + (mh * (WM / 2) + i) * 16 + fr, ks * 4 + fslot));
      if (mh == 0) {
#pragma unroll
        for (int ni = 0; ni < WN; ++ni)
          bf[ks][ni] = *(const short8*)(smB +
              swz8(wc * (WN * 16) + ni * 16 + fr, ks * 4 + fslot));
      }
      if (kt + 1 < nk) {
        if (ph == 0) stageA(cur ^ 1, kt + 1);
        if (ph == 1) stageB(cur ^ 1, kt + 1);
      }
      __builtin_amdgcn_s_barrier();
      asm volatile("s_waitcnt lgkmcnt(0)" ::: "memory");
      __builtin_amdgcn_sched_barrier(0);
      __builtin_amdgcn_s_setprio(1);
#pragma unroll
      for (int i = 0; i < WM / 2; ++i)
#pragma unroll
        for (int ni = 0; ni < WN; ++ni)
          acc[mh * (WM / 2) + i][ni] = __builtin_amdgcn_mfma_f32_16x16x32_bf16(
              af[i], bf[ks][ni], acc[mh * (WM / 2) + i][ni], 0, 0, 0);
      __builtin_amdgcn_s_setprio(0);
      __builtin_amdgcn_s_barrier();
    }
    if (kt + 1 < nk) {
      asm volatile("s_waitcnt vmcnt(0)" ::: "memory");
      __builtin_amdgcn_s_barrier();
    }
  }

  const int rq = (ln >> 4) << 2;
#pragma unroll
  for (int mi = 0; mi < WM; mi++) {
#pragma unroll
    for (int ni = 0; ni < WN; ni++) {
      const int row = m0 + wr * (WM * 16) + mi * 16 + rq;
      const int col = n0 + wc * (WN * 16) + ni * 16 + fr;
#pragma unroll
      for (int r = 0; r < 4; r++) {
        float v = acc[mi][ni][r];
        const size_t idx = (size_t)(row + r) * N + col;
        if (OUTBF) ((bfu*)Cout)[idx] = f2bf(v);
        else       ((float*)Cout)[idx] = v;
      }
    }
  }
}

// ---------------- full-row GEMM (proj + LN2 fusion): C[M,384] ---------------
__launch_bounds__(512)
__global__ void row_gemm(const bfu* __restrict__ A, const bfu* __restrict__ Bt,
                         const float* __restrict__ bias, const float* __restrict__ res,
                         const float* __restrict__ g, const float* __restrict__ be,
                         void* __restrict__ Cout, int K) {
  __shared__ bfu a_sm[4][128 * 32];
  __shared__ bfu b_sm[4][384 * 32];
  __shared__ float lnp[4][128][2];
  const int tid = threadIdx.x;
  const int wv = tid >> 6, ln = tid & 63;
  const int wr = wv >> 2, wc = wv & 3;
  const int fr = ln & 15, fslot = ln >> 4;
  const int m0 = blockIdx.x << 7;

  f32x4 acc[4][6];
#pragma unroll
  for (int i = 0; i < 4; i++)
#pragma unroll
    for (int j = 0; j < 6; j++) acc[i][j] = f32x4{0.f, 0.f, 0.f, 0.f};

  auto stage = [&](int buf, int kt) {
#pragma unroll
    for (int i = 0; i < 4; ++i) {
      const int c = wv * 4 + i;
      const int cc = (c < 8) ? c : (c - 8);
      const int p = cc * 1024 + (ln << 4);
      int r, colel;
      unswz(p, r, colel);
      const int col = kt * 32 + colel;
      if (c < 8)
        gld16(A + (size_t)(m0 + r) * K + col, (char*)a_sm[buf] + cc * 1024);
      else
        gld16(Bt + (size_t)r * K + col, (char*)b_sm[buf] + cc * 1024);
    }
  };

  const int nk = K >> 5;
#pragma unroll
  for (int i = 0; i < 3; ++i)
    if (i < nk) stage(i, i);

  for (int kt = 0; kt < nk; ++kt) {
    const int rem = nk - 1 - kt;
    if (rem >= 2)      asm volatile("s_waitcnt vmcnt(8)" ::: "memory");
    else if (rem == 1) asm volatile("s_waitcnt vmcnt(4)" ::: "memory");
    else               asm volatile("s_waitcnt vmcnt(0)" ::: "memory");
    __builtin_amdgcn_s_barrier();
    __builtin_amdgcn_sched_barrier(0);
    if (kt + 3 < nk) stage((kt + 3) & 3, kt + 3);
    const int cb = kt & 3;
    short8 af[4], bfr[6];
#pragma unroll
    for (int mi = 0; mi < 4; mi++)
      af[mi] = *(const short8*)((const char*)a_sm[cb] + swz(wr * 64 + mi * 16 + fr, fslot));
#pragma unroll
    for (int ni = 0; ni < 6; ni++)
      bfr[ni] = *(const short8*)((const char*)b_sm[cb] + swz(wc * 96 + ni * 16 + fr, fslot));
    __builtin_amdgcn_s_setprio(1);
#pragma unroll
    for (int mi = 0; mi < 4; mi++)
#pragma unroll
      for (int ni = 0; ni < 6; ni++)
        acc[mi][ni] = __builtin_amdgcn_mfma_f32_16x16x32_bf16(af[mi], bfr[ni], acc[mi][ni], 0, 0, 0);
    __builtin_amdgcn_s_setprio(0);
  }

  const int rq = (ln >> 4) << 2;
#pragma unroll
  for (int mi = 0; mi < 4; mi++) {
    const int row = wr * 64 + mi * 16 + rq;
#pragma unroll
    for (int ni = 0; ni < 6; ni++) {
      const int col = wc * 96 + ni * 16 + fr;
      const float bv = bias[col];
#pragma unroll
      for (int r = 0; r < 4; r++)
        acc[mi][ni][r] += bv + res[(size_t)(m0 + row + r) * 384 + col];
    }
  }

#pragma unroll
  for (int mi = 0; mi < 4; mi++) {
    float s[4] = {0.f, 0.f, 0.f, 0.f}, ss[4] = {0.f, 0.f, 0.f, 0.f};
#pragma unroll
    for (int ni = 0; ni < 6; ni++)
#pragma unroll
      for (int r = 0; r < 4; r++) {
        const float v = acc[mi][ni][r];
        s[r] += v; ss[r] += v * v;
      }
#pragma unroll
    for (int m = 1; m < 16; m <<= 1)
#pragma unroll
      for (int r = 0; r < 4; r++) {
        s[r] += __shfl_xor(s[r], m);
        ss[r] += __shfl_xor(ss[r], m);
      }
    if (fr == 0) {
#pragma unroll
      for (int r = 0; r < 4; r++) {
        lnp[wc][wr * 64 + mi * 16 + rq + r][0] = s[r];
        lnp[wc][wr * 64 + mi * 16 + rq + r][1] = ss[r];
      }
    }
  }
  __syncthreads();
#pragma unroll
  for (int mi = 0; mi < 4; mi++) {
#pragma unroll
    for (int r = 0; r < 4; r++) {
      const int row = wr * 64 + mi * 16 + rq + r;
      const float sm = lnp[0][row][0] + lnp[1][row][0] + lnp[2][row][0] + lnp[3][row][0];
      const float sq = lnp[0][row][1] + lnp[1][row][1] + lnp[2][row][1] + lnp[3][row][1];
      const float mean = sm * (1.f / 384.f);
      const float rs = rsqrtf(sq * (1.f / 384.f) - mean * mean + 1e-5f);
#pragma unroll
      for (int ni = 0; ni < 6; ni++) {
        const int col = wc * 96 + ni * 16 + fr;
        ((bfu*)Cout)[(size_t)(m0 + row) * 384 + col] =
            f2bf((acc[mi][ni][r] - mean) * rs * g[col] + be[col]);
      }
    }
  }
}

// ---------------- fused causal attention: 1 block per (b,h), 8 waves --------
#define KPAD 72
#define VPAD 264
#define PPAD 264

__launch_bounds__(512)
__global__ void attn_kernel(const bfu* __restrict__ qkv, bfu* __restrict__ ob) {
  __shared__ bfu k_sm[256 * KPAD];
  __shared__ bfu vt_sm[64 * VPAD];
  __shared__ bfu p_sm[8 * 16 * PPAD];
  const int b = blockIdx.x / 6, h = blockIdx.x - b * 6;
  const int tid = threadIdx.x;
  const int wv = tid >> 6, ln = tid & 63;
  const int fr = ln & 15, fc = (ln >> 4) << 3;
  const size_t inbase = (size_t)b * 256 * 1152 + h * 64;
  const bfu* qb = qkv + inbase;
  const bfu* kb = qkv + inbase + 384;
  const bfu* vb = qkv + inbase + 768;
  const size_t obase = (size_t)b * 256 * 384 + h * 64;

  {
    const int row = tid >> 1;
    const int dh = (tid & 1) << 5;
    const bfu* kg = kb + (size_t)row * 1152 + dh;
    const bfu* vg = vb + (size_t)row * 1152 + dh;
#pragma unroll
    for (int i = 0; i < 4; i++) {
      short8 t8 = *(const short8*)(kg + i * 8);
      *(short8*)&k_sm[row * KPAD + dh + i * 8] = t8;
      short8 v8 = *(const short8*)(vg + i * 8);
#pragma unroll
      for (int j = 0; j < 8; j++)
        vt_sm[(dh + i * 8 + j) * VPAD + row] = (bfu)v8[j];
    }
  }
  __syncthreads();

  bfu* pw = &p_sm[wv * 16 * PPAD];
  const int rq = (ln >> 4) << 2;

#pragma unroll
  for (int si = 0; si < 2; ++si) {
    const int s = si ? (15 - wv) : wv;
    const int qr0 = s << 4;
    const int nf = s + 1;
    short8 aq[2];
#pragma unroll
    for (int dc = 0; dc < 2; dc++)
      aq[dc] = *(const short8*)(qb + (size_t)(qr0 + fr) * 1152 + dc * 32 + fc);

    f32x4 sacc[16];
#pragma unroll
    for (int f = 0; f < 16; f++) sacc[f] = f32x4{0.f, 0.f, 0.f, 0.f};
#pragma unroll
    for (int f = 0; f < 16; f++) if (f < nf) {
#pragma unroll
      for (int dc = 0; dc < 2; dc++) {
        short8 kf = *(const short8*)&k_sm[(f * 16 + fr) * KPAD + dc * 32 + fc];
        sacc[f] = __builtin_amdgcn_mfma_f32_16x16x32_bf16(aq[dc], kf, sacc[f], 0, 0, 0);
      }
    }
    float mr[4] = {-3e38f, -3e38f, -3e38f, -3e38f};
#pragma unroll
    for (int f = 0; f < 16; f++) if (f < nf) {
#pragma unroll
      for (int r = 0; r < 4; r++) {
        float sv = sacc[f][r] * 0.125f;
        if (f * 16 + fr > qr0 + rq + r) sv = -3e38f;
        sacc[f][r] = sv;
        mr[r] = fmaxf(mr[r], sv);
      }
    }
#pragma unroll
    for (int msk = 1; msk < 16; msk <<= 1) {
#pragma unroll
      for (int r = 0; r < 4; r++) mr[r] = fmaxf(mr[r], __shfl_xor(mr[r], msk));
    }
    float ls[4] = {0.f, 0.f, 0.f, 0.f};
#pragma unroll
    for (int f = 0; f < 16; f++) if (f < nf) {
#pragma unroll
      for (int r = 0; r < 4; r++) {
        float p = __expf(sacc[f][r] - mr[r]);
        sacc[f][r] = p;
        ls[r] += p;
      }
    }
#pragma unroll
    for (int msk = 1; msk < 16; msk <<= 1) {
#pragma unroll
      for (int r = 0; r < 4; r++) ls[r] += __shfl_xor(ls[r], msk);
    }
#pragma unroll
    for (int f = 0; f < 16; f++) if (f < nf) {
#pragma unroll
      for (int r = 0; r < 4; r++)
        pw[(rq + r) * PPAD + f * 16 + fr] = f2bf(sacc[f][r]);
    }
    if (nf & 1) {
#pragma unroll
      for (int r = 0; r < 4; r++) pw[(rq + r) * PPAD + nf * 16 + fr] = 0;
    }
    f32x4 oc[4];
#pragma unroll
    for (int n = 0; n < 4; n++) oc[n] = f32x4{0.f, 0.f, 0.f, 0.f};
    const int kcs = (nf + 1) >> 1;
#pragma unroll
    for (int kc = 0; kc < 8; ++kc) if (kc < kcs) {
      short8 pa = *(const short8*)&pw[fr * PPAD + kc * 32 + fc];
#pragma unroll
      for (int n = 0; n < 4; n++) {
        short8 vf = *(const short8*)&vt_sm[(n * 16 + fr) * VPAD + kc * 32 + fc];
        oc[n] = __builtin_amdgcn_mfma_f32_16x16x32_bf16(pa, vf, oc[n], 0, 0, 0);
      }
    }
    float inv[4];
#pragma unroll
    for (int r = 0; r < 4; r++) inv[r] = 1.f / ls[r];
#pragma unroll
    for (int n = 0; n < 4; n++) {
#pragma unroll
      for (int r = 0; r < 4; r++)
        ob[obase + (size_t)(qr0 + rq + r) * 384 + n * 16 + fr] = f2bf(oc[n][r] * inv[r]);
    }
  }
}

// ---------------- orchestration ---------------------------------------------
extern "C" void kernel_launch(void* const* d_in, const int* in_sizes, int n_in,
                              void* d_out, int out_size, void* d_ws, size_t ws_size,
                              hipStream_t stream) {
  const float* x   = (const float*)d_in[0];
  const float* Wq  = (const float*)d_in[1];
  const float* Wk  = (const float*)d_in[2];
  const float* Wv  = (const float*)d_in[3];
  const float* Wo  = (const float*)d_in[4];
  const float* bo  = (const float*)d_in[5];
  const float* W1  = (const float*)d_in[6];
  const float* b1  = (const float*)d_in[7];
  const float* W2  = (const float*)d_in[8];
  const float* b2  = (const float*)d_in[9];
  const float* g1  = (const float*)d_in[10];
  const float* be1 = (const float*)d_in[11];
  const float* g2  = (const float*)d_in[12];
  const float* be2 = (const float*)d_in[13];
  float* out = (float*)d_out;
  char* ws = (char*)d_ws;

  bfu* wqkvT = (bfu*)(ws + 0);          // 1152x384 bf16
  bfu* woT   = (bfu*)(ws + 884736);
  bfu* w1f   = (bfu*)(ws + 1179648);    // frag-major W1
  bfu* w2f   = (bfu*)(ws + 2359296);    // frag-major W2
  char* H    = ws + 3538944;            // 50.3 MB: h2
  char* BIG  = H + 50331648;            // 201.3 MB
  bfu* hb    = (bfu*)BIG;
  bfu* qkvb  = (bfu*)(BIG + 50331648);
  bfu* attnb = (bfu*)BIG;
  bfu* h2b   = (bfu*)H;

  // 1) weight prep (one launch)
  transpose_all<<<6912, 256, 0, stream>>>(Wq, Wk, Wv, Wo, W1, W2, wqkvT, woT, w1f, w2f);

  // 2) LN1
  ln_kernel<<<16384, 256, 0, stream>>>(x, g1, be1, hb);

  // 3) fused QKV GEMM (N=1152): 256 m-tiles x 6 n-tiles of 256x192
  gemm_ph<8, 3, 1><<<1536, 512, 0, stream>>>(hb, wqkvT, qkvb, 1152, 384, 6);

  // 4) fused causal attention
  attn_kernel<<<1536, 512, 0, stream>>>(qkvb, attnb);

  // 5) proj + bias + residual(x) + LN2 fused -> h2 (bf16)
  row_gemm<<<512, 512, 0, stream>>>(attnb, woT, bo, x, g2, be2, h2b, 384);

  // 6+7) fused FFN: out = relu(h2@W1+b1)@W2 + b2 + x
  ffn_fused<<<1024, 512, 0, stream>>>(h2b, w1f, w2f, b1, b2, x, out);
}

// Round 9
// 509.582 us; speedup vs baseline: 1.0301x; 1.0301x over previous
//
#include <hip/hip_runtime.h>
#include <hip/hip_bf16.h>

typedef unsigned short bfu;
typedef __attribute__((ext_vector_type(8))) short short8;
typedef __attribute__((ext_vector_type(4))) float f32x4;

__device__ __forceinline__ bfu f2bf(float f) {
  return __builtin_bit_cast(bfu, __float2bfloat16(f));
}

__device__ __forceinline__ void gld16(const void* g, void* l) {
  __builtin_amdgcn_global_load_lds(
      (const __attribute__((address_space(1))) void*)g,
      (__attribute__((address_space(3))) void*)l, 16, 0, 0);
}

// ---- swizzle for [rows][64]-bf16 tiles (128B rows, 8 x 16B slots per row)
__device__ __forceinline__ int swz8(int row, int sl) {
  return (row << 7) + (((sl ^ (row & 7)) & 7) << 4);
}

// ---- swizzle for [rows][32]-bf16 tiles (64B rows) used by row_gemm --------
__device__ __forceinline__ int swz(int row, int slot) {
  const int unit = row >> 1;
  const int s8 = ((row & 1) << 2) | slot;
  return (unit << 7) + (((s8 ^ unit) & 7) << 4) + ((s8 >> 3) << 7);
}
__device__ __forceinline__ void unswz(int p, int& row, int& colel) {
  const int unit = p >> 7;
  const int s8 = ((p >> 4) & 7) ^ (unit & 7);
  row = (unit << 1) | (s8 >> 2);
  colel = (s8 & 3) << 3;
}

// ---------------- all weight transposes in ONE launch -----------------------
__global__ void transpose_all(const float* __restrict__ Wq, const float* __restrict__ Wk,
                              const float* __restrict__ Wv, const float* __restrict__ Wo,
                              const float* __restrict__ W1, const float* __restrict__ W2,
                              bfu* __restrict__ wqkvT, bfu* __restrict__ woT,
                              bfu* __restrict__ w1T, bfu* __restrict__ w2T) {
  int idx = blockIdx.x * 256 + threadIdx.x;
  if (idx < 4 * 147456) {
    int r = idx / 147456, i = idx - r * 147456;
    int k = i / 384, n = i - k * 384;
    const float* W = r == 0 ? Wq : r == 1 ? Wk : r == 2 ? Wv : Wo;
    bfu* dst = r < 3 ? wqkvT + r * 147456 : woT;
    dst[n * 384 + k] = f2bf(W[i]);
  } else if (idx < 4 * 147456 + 589824) {
    int i = idx - 4 * 147456;                    // W1: [384][1536]
    int k = i / 1536, n = i - k * 1536;
    w1T[n * 384 + k] = f2bf(W1[i]);
  } else if (idx < 4 * 147456 + 2 * 589824) {
    int i = idx - 4 * 147456 - 589824;           // W2: [1536][384]
    int k = i / 384, n = i - k * 384;
    w2T[(size_t)n * 1536 + k] = f2bf(W2[i]);
  }
}

// ---------------- LayerNorm: one wave per row of 384 ------------------------
__launch_bounds__(256)
__global__ void ln_kernel(const float* __restrict__ in, const float* __restrict__ g,
                          const float* __restrict__ be, bfu* __restrict__ out) {
  const int wv = threadIdx.x >> 6, ln = threadIdx.x & 63;
  const size_t row = (size_t)blockIdx.x * 4 + wv;
  const float* p = in + row * 384;
  float v[6], s = 0.f, ss = 0.f;
#pragma unroll
  for (int i = 0; i < 6; i++) { v[i] = p[i * 64 + ln]; s += v[i]; ss += v[i] * v[i]; }
#pragma unroll
  for (int m = 1; m < 64; m <<= 1) { s += __shfl_xor(s, m); ss += __shfl_xor(ss, m); }
  const float mean = s * (1.f / 384.f);
  const float rs = rsqrtf(ss * (1.f / 384.f) - mean * mean + 1e-5f);
  bfu* q = out + row * 384;
#pragma unroll
  for (int i = 0; i < 6; i++) {
    const int c = i * 64 + ln;
    q[c] = f2bf((v[i] - mean) * rs * g[c] + be[c]);
  }
}

// ---------------- counted-vmcnt spread-stage GEMM ---------------------------
// BM=256, BN=128, BK=64, 512 thr = 8 waves (2m x 4n), wave tile 128x32.
// 3 LDS bufs (K-tile k in buf k%3). Group k = 4 phases {mh, nh}; each phase:
// ds_read frags -> stage ONE half-tile of K-tile k+2 into buf (k+2)%3 ->
// barrier -> lgkm0 -> 8 MFMA -> barrier. Stage loads spread [2,2,1,1] over
// the 4 phases; vmcnt(6) ONLY at group tails (never 0 until the end).
// Race-free: read-buf k%3, stage-buf (k+2)%3, next-read (k+1)%3 all distinct.
template <int BIAS, int RELU, int RES, int OUTBF>
__launch_bounds__(512)
__global__ void gemm3b(const bfu* __restrict__ A, const bfu* __restrict__ Bt,
                       const float* __restrict__ bias, const float* __restrict__ res,
                       void* __restrict__ Cout, int N, int K, int ntn) {
  __shared__ char sm[3 * 49152];    // per buf: A[256][64] (32KB) + B[128][64] (16KB)
  const int tid = threadIdx.x;
  const int wv = tid >> 6, ln = tid & 63;
  const int cpx = gridDim.x >> 3;   // grid % 8 == 0 at all call sites
  const int wg = (blockIdx.x & 7) * cpx + (blockIdx.x >> 3);
  const int bm = wg / ntn, bn = wg - bm * ntn;
  const int m0 = bm << 8, n0 = bn << 7;
  const int wr = wv >> 2, wc = wv & 3;       // wave tile: rows wr*128+128, cols wc*32+32
  const int fr = ln & 15, fslot = ln >> 4;
  const int lr = ln >> 3, lsl = (ln & 7) ^ lr;   // staging row-in-chunk / logical slot

  f32x4 acc[8][2];
#pragma unroll
  for (int i = 0; i < 8; i++)
#pragma unroll
    for (int j = 0; j < 2; j++) acc[i][j] = f32x4{0.f, 0.f, 0.f, 0.f};

  auto stageA = [&](int dbuf, int kt, int half) {  // 2 loads: A chunks
    char* smA = sm + dbuf * 49152;
    const int col = (kt << 6) + (lsl << 3);
#pragma unroll
    for (int i = 0; i < 2; ++i) {
      const int c = (wv << 2) + (half << 1) + i;   // 0..31
      gld16(A + (size_t)(m0 + (c << 3) + lr) * K + col, smA + (c << 10));
    }
  };
  auto stageB = [&](int dbuf, int kt, int j) {     // 1 load: B chunk
    char* smB = sm + dbuf * 49152 + 32768;
    const int col = (kt << 6) + (lsl << 3);
    const int c = (wv << 1) + j;                   // 0..15
    gld16(Bt + (size_t)(n0 + (c << 3) + lr) * K + col, smB + (c << 10));
  };

  const int nk = K >> 6;
  // prologue: K-tiles 0 -> buf0, 1 -> buf1 (6 loads each)
  stageA(0, 0, 0); stageA(0, 0, 1); stageB(0, 0, 0); stageB(0, 0, 1);
  stageA(1, 1, 0); stageA(1, 1, 1); stageB(1, 1, 0); stageB(1, 1, 1);
  asm volatile("s_waitcnt vmcnt(6)" ::: "memory");  // K-tile 0 ready; 1 in flight
  __builtin_amdgcn_s_barrier();

  int cb = 0;
  for (int k = 0; k < nk; ++k) {
    const char* smA = sm + cb * 49152;
    const char* smB = smA + 32768;
    int sb = cb + 2; if (sb >= 3) sb -= 3;
    const bool st = (k + 2) < nk;
#pragma unroll
    for (int mh = 0; mh < 2; ++mh) {
      short8 af[4][2];
#pragma unroll
      for (int i = 0; i < 4; ++i)
#pragma unroll
        for (int ks = 0; ks < 2; ++ks)
          af[i][ks] = *(const short8*)(smA +
              swz8(wr * 128 + mh * 64 + i * 16 + fr, ks * 4 + fslot));
#pragma unroll
      for (int nh = 0; nh < 2; ++nh) {
        short8 bf[2];
#pragma unroll
        for (int ks = 0; ks < 2; ++ks)
          bf[ks] = *(const short8*)(smB + swz8(wc * 32 + nh * 16 + fr, ks * 4 + fslot));
        if (st) {
          if (mh == 0 && nh == 0) stageA(sb, k + 2, 0);
          if (mh == 0 && nh == 1) stageA(sb, k + 2, 1);
          if (mh == 1 && nh == 0) stageB(sb, k + 2, 0);
          if (mh == 1 && nh == 1) stageB(sb, k + 2, 1);
        }
        __builtin_amdgcn_s_barrier();
        asm volatile("s_waitcnt lgkmcnt(0)" ::: "memory");
        __builtin_amdgcn_sched_barrier(0);
        __builtin_amdgcn_s_setprio(1);
#pragma unroll
        for (int i = 0; i < 4; ++i)
#pragma unroll
          for (int ks = 0; ks < 2; ++ks)
            acc[mh * 4 + i][nh] = __builtin_amdgcn_mfma_f32_16x16x32_bf16(
                af[i][ks], bf[ks], acc[mh * 4 + i][nh], 0, 0, 0);
        __builtin_amdgcn_s_setprio(0);
        if (mh == 1 && nh == 1 && k + 1 < nk) {
          // group tail: publish K-tile k+1 (G(k-1) drained); leave G(k) in flight
          if (st) asm volatile("s_waitcnt vmcnt(6)" ::: "memory");
          else    asm volatile("s_waitcnt vmcnt(0)" ::: "memory");
        }
        __builtin_amdgcn_s_barrier();
      }
    }
    cb = (cb + 1 == 3) ? 0 : cb + 1;
  }

  const int rq = (ln >> 4) << 2;
#pragma unroll
  for (int mi = 0; mi < 8; mi++) {
#pragma unroll
    for (int ni = 0; ni < 2; ni++) {
      const int row = m0 + wr * 128 + mi * 16 + rq;
      const int col = n0 + wc * 32 + ni * 16 + fr;
      float bv = 0.f;
      if (BIAS) bv = bias[col];
#pragma unroll
      for (int r = 0; r < 4; r++) {
        float v = acc[mi][ni][r] + bv;
        if (RELU) v = fmaxf(v, 0.f);
        const size_t idx = (size_t)(row + r) * N + col;
        if (RES) v += res[idx];
        if (OUTBF) ((bfu*)Cout)[idx] = f2bf(v);
        else       ((float*)Cout)[idx] = v;
      }
    }
  }
}

// ---------------- full-row GEMM (proj + LN2 fusion): C[M,384] ---------------
__launch_bounds__(512)
__global__ void row_gemm(const bfu* __restrict__ A, const bfu* __restrict__ Bt,
                         const float* __restrict__ bias, const float* __restrict__ res,
                         const float* __restrict__ g, const float* __restrict__ be,
                         void* __restrict__ Cout, int K) {
  __shared__ bfu a_sm[4][128 * 32];
  __shared__ bfu b_sm[4][384 * 32];
  __shared__ float lnp[4][128][2];
  const int tid = threadIdx.x;
  const int wv = tid >> 6, ln = tid & 63;
  const int wr = wv >> 2, wc = wv & 3;
  const int fr = ln & 15, fslot = ln >> 4;
  const int m0 = blockIdx.x << 7;

  f32x4 acc[4][6];
#pragma unroll
  for (int i = 0; i < 4; i++)
#pragma unroll
    for (int j = 0; j < 6; j++) acc[i][j] = f32x4{0.f, 0.f, 0.f, 0.f};

  auto stage = [&](int buf, int kt) {
#pragma unroll
    for (int i = 0; i < 4; ++i) {
      const int c = wv * 4 + i;
      const int cc = (c < 8) ? c : (c - 8);
      const int p = cc * 1024 + (ln << 4);
      int r, colel;
      unswz(p, r, colel);
      const int col = kt * 32 + colel;
      if (c < 8)
        gld16(A + (size_t)(m0 + r) * K + col, (char*)a_sm[buf] + cc * 1024);
      else
        gld16(Bt + (size_t)r * K + col, (char*)b_sm[buf] + cc * 1024);
    }
  };

  const int nk = K >> 5;
#pragma unroll
  for (int i = 0; i < 3; ++i)
    if (i < nk) stage(i, i);

  for (int kt = 0; kt < nk; ++kt) {
    const int rem = nk - 1 - kt;
    if (rem >= 2)      asm volatile("s_waitcnt vmcnt(8)" ::: "memory");
    else if (rem == 1) asm volatile("s_waitcnt vmcnt(4)" ::: "memory");
    else               asm volatile("s_waitcnt vmcnt(0)" ::: "memory");
    __builtin_amdgcn_s_barrier();
    __builtin_amdgcn_sched_barrier(0);
    if (kt + 3 < nk) stage((kt + 3) & 3, kt + 3);
    const int cb = kt & 3;
    short8 af[4], bfr[6];
#pragma unroll
    for (int mi = 0; mi < 4; mi++)
      af[mi] = *(const short8*)((const char*)a_sm[cb] + swz(wr * 64 + mi * 16 + fr, fslot));
#pragma unroll
    for (int ni = 0; ni < 6; ni++)
      bfr[ni] = *(const short8*)((const char*)b_sm[cb] + swz(wc * 96 + ni * 16 + fr, fslot));
    __builtin_amdgcn_s_setprio(1);
#pragma unroll
    for (int mi = 0; mi < 4; mi++)
#pragma unroll
      for (int ni = 0; ni < 6; ni++)
        acc[mi][ni] = __builtin_amdgcn_mfma_f32_16x16x32_bf16(af[mi], bfr[ni], acc[mi][ni], 0, 0, 0);
    __builtin_amdgcn_s_setprio(0);
  }

  const int rq = (ln >> 4) << 2;
#pragma unroll
  for (int mi = 0; mi < 4; mi++) {
    const int row = wr * 64 + mi * 16 + rq;
#pragma unroll
    for (int ni = 0; ni < 6; ni++) {
      const int col = wc * 96 + ni * 16 + fr;
      const float bv = bias[col];
#pragma unroll
      for (int r = 0; r < 4; r++)
        acc[mi][ni][r] += bv + res[(size_t)(m0 + row + r) * 384 + col];
    }
  }

#pragma unroll
  for (int mi = 0; mi < 4; mi++) {
    float s[4] = {0.f, 0.f, 0.f, 0.f}, ss[4] = {0.f, 0.f, 0.f, 0.f};
#pragma unroll
    for (int ni = 0; ni < 6; ni++)
#pragma unroll
      for (int r = 0; r < 4; r++) {
        const float v = acc[mi][ni][r];
        s[r] += v; ss[r] += v * v;
      }
#pragma unroll
    for (int m = 1; m < 16; m <<= 1)
#pragma unroll
      for (int r = 0; r < 4; r++) {
        s[r] += __shfl_xor(s[r], m);
        ss[r] += __shfl_xor(ss[r], m);
      }
    if (fr == 0) {
#pragma unroll
      for (int r = 0; r < 4; r++) {
        lnp[wc][wr * 64 + mi * 16 + rq + r][0] = s[r];
        lnp[wc][wr * 64 + mi * 16 + rq + r][1] = ss[r];
      }
    }
  }
  __syncthreads();
#pragma unroll
  for (int mi = 0; mi < 4; mi++) {
#pragma unroll
    for (int r = 0; r < 4; r++) {
      const int row = wr * 64 + mi * 16 + rq + r;
      const float sm = lnp[0][row][0] + lnp[1][row][0] + lnp[2][row][0] + lnp[3][row][0];
      const float sq = lnp[0][row][1] + lnp[1][row][1] + lnp[2][row][1] + lnp[3][row][1];
      const float mean = sm * (1.f / 384.f);
      const float rs = rsqrtf(sq * (1.f / 384.f) - mean * mean + 1e-5f);
#pragma unroll
      for (int ni = 0; ni < 6; ni++) {
        const int col = wc * 96 + ni * 16 + fr;
        ((bfu*)Cout)[(size_t)(m0 + row) * 384 + col] =
            f2bf((acc[mi][ni][r] - mean) * rs * g[col] + be[col]);
      }
    }
  }
}

// ---------------- fused causal attention: 1 block per (b,h), 8 waves --------
#define KPAD 72
#define VPAD 264
#define PPAD 264

__launch_bounds__(512)
__global__ void attn_kernel(const bfu* __restrict__ qkv, bfu* __restrict__ ob) {
  __shared__ bfu k_sm[256 * KPAD];
  __shared__ bfu vt_sm[64 * VPAD];
  __shared__ bfu p_sm[8 * 16 * PPAD];
  const int b = blockIdx.x / 6, h = blockIdx.x - b * 6;
  const int tid = threadIdx.x;
  const int wv = tid >> 6, ln = tid & 63;
  const int fr = ln & 15, fc = (ln >> 4) << 3;
  const size_t inbase = (size_t)b * 256 * 1152 + h * 64;
  const bfu* qb = qkv + inbase;
  const bfu* kb = qkv + inbase + 384;
  const bfu* vb = qkv + inbase + 768;
  const size_t obase = (size_t)b * 256 * 384 + h * 64;

  {
    const int row = tid >> 1;
    const int dh = (tid & 1) << 5;
    const bfu* kg = kb + (size_t)row * 1152 + dh;
    const bfu* vg = vb + (size_t)row * 1152 + dh;
#pragma unroll
    for (int i = 0; i < 4; i++) {
      short8 t8 = *(const short8*)(kg + i * 8);
      *(short8*)&k_sm[row * KPAD + dh + i * 8] = t8;
      short8 v8 = *(const short8*)(vg + i * 8);
#pragma unroll
      for (int j = 0; j < 8; j++)
        vt_sm[(dh + i * 8 + j) * VPAD + row] = (bfu)v8[j];
    }
  }
  __syncthreads();

  bfu* pw = &p_sm[wv * 16 * PPAD];
  const int rq = (ln >> 4) << 2;

#pragma unroll
  for (int si = 0; si < 2; ++si) {
    const int s = si ? (15 - wv) : wv;
    const int qr0 = s << 4;
    const int nf = s + 1;
    short8 aq[2];
#pragma unroll
    for (int dc = 0; dc < 2; dc++)
      aq[dc] = *(const short8*)(qb + (size_t)(qr0 + fr) * 1152 + dc * 32 + fc);

    f32x4 sacc[16];
#pragma unroll
    for (int f = 0; f < 16; f++) sacc[f] = f32x4{0.f, 0.f, 0.f, 0.f};
#pragma unroll
    for (int f = 0; f < 16; f++) if (f < nf) {
#pragma unroll
      for (int dc = 0; dc < 2; dc++) {
        short8 kf = *(const short8*)&k_sm[(f * 16 + fr) * KPAD + dc * 32 + fc];
        sacc[f] = __builtin_amdgcn_mfma_f32_16x16x32_bf16(aq[dc], kf, sacc[f], 0, 0, 0);
      }
    }
    float mr[4] = {-3e38f, -3e38f, -3e38f, -3e38f};
#pragma unroll
    for (int f = 0; f < 16; f++) if (f < nf) {
#pragma unroll
      for (int r = 0; r < 4; r++) {
        float sv = sacc[f][r] * 0.125f;
        if (f * 16 + fr > qr0 + rq + r) sv = -3e38f;
        sacc[f][r] = sv;
        mr[r] = fmaxf(mr[r], sv);
      }
    }
#pragma unroll
    for (int msk = 1; msk < 16; msk <<= 1) {
#pragma unroll
      for (int r = 0; r < 4; r++) mr[r] = fmaxf(mr[r], __shfl_xor(mr[r], msk));
    }
    float ls[4] = {0.f, 0.f, 0.f, 0.f};
#pragma unroll
    for (int f = 0; f < 16; f++) if (f < nf) {
#pragma unroll
      for (int r = 0; r < 4; r++) {
        float p = __expf(sacc[f][r] - mr[r]);
        sacc[f][r] = p;
        ls[r] += p;
      }
    }
#pragma unroll
    for (int msk = 1; msk < 16; msk <<= 1) {
#pragma unroll
      for (int r = 0; r < 4; r++) ls[r] += __shfl_xor(ls[r], msk);
    }
#pragma unroll
    for (int f = 0; f < 16; f++) if (f < nf) {
#pragma unroll
      for (int r = 0; r < 4; r++)
        pw[(rq + r) * PPAD + f * 16 + fr] = f2bf(sacc[f][r]);
    }
    if (nf & 1) {
#pragma unroll
      for (int r = 0; r < 4; r++) pw[(rq + r) * PPAD + nf * 16 + fr] = 0;
    }
    f32x4 oc[4];
#pragma unroll
    for (int n = 0; n < 4; n++) oc[n] = f32x4{0.f, 0.f, 0.f, 0.f};
    const int kcs = (nf + 1) >> 1;
#pragma unroll
    for (int kc = 0; kc < 8; ++kc) if (kc < kcs) {
      short8 pa = *(const short8*)&pw[fr * PPAD + kc * 32 + fc];
#pragma unroll
      for (int n = 0; n < 4; n++) {
        short8 vf = *(const short8*)&vt_sm[(n * 16 + fr) * VPAD + kc * 32 + fc];
        oc[n] = __builtin_amdgcn_mfma_f32_16x16x32_bf16(pa, vf, oc[n], 0, 0, 0);
      }
    }
    float inv[4];
#pragma unroll
    for (int r = 0; r < 4; r++) inv[r] = 1.f / ls[r];
#pragma unroll
    for (int n = 0; n < 4; n++) {
#pragma unroll
      for (int r = 0; r < 4; r++)
        ob[obase + (size_t)(qr0 + rq + r) * 384 + n * 16 + fr] = f2bf(oc[n][r] * inv[r]);
    }
  }
}

// ---------------- orchestration ---------------------------------------------
extern "C" void kernel_launch(void* const* d_in, const int* in_sizes, int n_in,
                              void* d_out, int out_size, void* d_ws, size_t ws_size,
                              hipStream_t stream) {
  const float* x   = (const float*)d_in[0];
  const float* Wq  = (const float*)d_in[1];
  const float* Wk  = (const float*)d_in[2];
  const float* Wv  = (const float*)d_in[3];
  const float* Wo  = (const float*)d_in[4];
  const float* bo  = (const float*)d_in[5];
  const float* W1  = (const float*)d_in[6];
  const float* b1  = (const float*)d_in[7];
  const float* W2  = (const float*)d_in[8];
  const float* b2  = (const float*)d_in[9];
  const float* g1  = (const float*)d_in[10];
  const float* be1 = (const float*)d_in[11];
  const float* g2  = (const float*)d_in[12];
  const float* be2 = (const float*)d_in[13];
  float* out = (float*)d_out;
  char* ws = (char*)d_ws;

  bfu* wqkvT = (bfu*)(ws + 0);          // 1152x384 bf16
  bfu* woT   = (bfu*)(ws + 884736);
  bfu* w1T   = (bfu*)(ws + 1179648);    // 1536x384
  bfu* w2T   = (bfu*)(ws + 2359296);    // 384x1536
  char* H    = ws + 3538944;            // 50.3 MB: h2
  char* BIG  = H + 50331648;            // 201.3 MB
  bfu* hb    = (bfu*)BIG;
  bfu* qkvb  = (bfu*)(BIG + 50331648);
  bfu* attnb = (bfu*)BIG;
  bfu* h2b   = (bfu*)H;
  bfu* ab    = (bfu*)BIG;

  // 1) all weight transposes (one launch)
  transpose_all<<<6912, 256, 0, stream>>>(Wq, Wk, Wv, Wo, W1, W2, wqkvT, woT, w1T, w2T);

  // 2) LN1
  ln_kernel<<<16384, 256, 0, stream>>>(x, g1, be1, hb);

  // 3) fused QKV GEMM (N=1152): 256 m-tiles x 9 n-tiles of 256x128
  gemm3b<0, 0, 0, 1><<<2304, 512, 0, stream>>>(hb, wqkvT, nullptr, nullptr, qkvb, 1152, 384, 9);

  // 4) fused causal attention
  attn_kernel<<<1536, 512, 0, stream>>>(qkvb, attnb);

  // 5) proj + bias + residual(x) + LN2 fused -> h2 (bf16)
  row_gemm<<<512, 512, 0, stream>>>(attnb, woT, bo, x, g2, be2, h2b, 384);

  // 6) FFN1 (+bias+ReLU): 256 x 12 tiles of 256x128
  gemm3b<1, 1, 0, 1><<<3072, 512, 0, stream>>>(h2b, w1T, b1, nullptr, ab, 1536, 384, 12);

  // 7) FFN2 + bias + residual(x) -> out (fp32): 256 x 3 tiles of 256x128
  gemm3b<1, 0, 1, 0><<<768, 512, 0, stream>>>(ab, w2T, b2, x, out, 384, 1536, 3);
}